// Round 2
// baseline (463.680 us; speedup 1.0000x reference)
//
#include <hip/hip_runtime.h>

#define E_DIM 64
#define N_E   1024
#define N_PTS 32768

// d_out layout (floats):
//   [0]                      loss
//   [1 .. 1+2097152)         z_q_out (B,C,H,W)
//   [2097153]                perplexity
//   [2097154 .. +33554432)   min_encodings (N, n_e)
//   [35651586 .. +32768)     indices (as float)
#define OFF_ZQ   1
#define OFF_PERP 2097153
#define OFF_OH   2097154
#define OFF_IDX  35651586

// d_ws layout (bytes):
#define WS_LOSS    0        // float
#define WS_FIXCNT  4        // uint
#define WS_COUNTS  256      // uint[1024]
#define WS_NORMS   8192     // float[1024]
#define WS_IDX     16384    // int[32768]      (ends 147456)
#define WS_FIXLIST 147456   // int[8192]       (ends 180224)
#define FIXCAP     8192

#define CHUNK  128
#define LDSPAD 68

// numpy pairwise_sum replication for n=64 over squares:
// r[j] = sum_m fl32(a[8m+j]^2) accumulated sequentially (m ascending),
// result = ((r0+r1)+(r2+r3))+((r4+r5)+(r6+r7)).  fp32, NO contraction.
__device__ __forceinline__ float np_sum64_sq(const float* a) {
#pragma clang fp contract(off)
    float r0 = a[0] * a[0];
    float r1 = a[1] * a[1];
    float r2 = a[2] * a[2];
    float r3 = a[3] * a[3];
    float r4 = a[4] * a[4];
    float r5 = a[5] * a[5];
    float r6 = a[6] * a[6];
    float r7 = a[7] * a[7];
#pragma unroll
    for (int m = 1; m < 8; ++m) {
        r0 += a[8 * m + 0] * a[8 * m + 0];
        r1 += a[8 * m + 1] * a[8 * m + 1];
        r2 += a[8 * m + 2] * a[8 * m + 2];
        r3 += a[8 * m + 3] * a[8 * m + 3];
        r4 += a[8 * m + 4] * a[8 * m + 4];
        r5 += a[8 * m + 5] * a[8 * m + 5];
        r6 += a[8 * m + 6] * a[8 * m + 6];
        r7 += a[8 * m + 7] * a[8 * m + 7];
    }
    return ((r0 + r1) + (r2 + r3)) + ((r4 + r5) + (r6 + r7));
}

__global__ void knorm_kernel(const float* __restrict__ emb, float* __restrict__ norms) {
    int k = blockIdx.x * blockDim.x + threadIdx.x;
    if (k >= N_E) return;
    float er[E_DIM];
    const float4* e4 = reinterpret_cast<const float4*>(emb) + (size_t)k * (E_DIM / 4);
#pragma unroll
    for (int i = 0; i < E_DIM / 4; ++i)
        *reinterpret_cast<float4*>(&er[i * 4]) = e4[i];
    norms[k] = np_sum64_sq(er);
}

// Phase A: 512 blocks x 256 threads. 64 points/block, 4 threads/point.
// Computes d = fl32( fl32(nz + ne_k) - 2*dot32 ) with fast fp32 dot;
// tracks top-2; near-ties (margin < 4e-5, ~2 grid ulps) go to Phase B.
__global__ __launch_bounds__(256) void kargmin_kernel(
    const float* __restrict__ z, const float* __restrict__ emb,
    const float* __restrict__ norms,
    int* __restrict__ idx, unsigned int* __restrict__ counts,
    float* __restrict__ out_idx,
    unsigned int* __restrict__ fixcnt, int* __restrict__ fixlist)
{
    __shared__ float se[CHUNK * LDSPAD];
    __shared__ float sn[CHUNK];
    const int tid = threadIdx.x;
    const int s = tid & 3;        // code-split lane
    const int lp = tid >> 2;      // local point 0..63
    const int p = blockIdx.x * 64 + lp;
    const int b = p >> 10;
    const int hw = p & 1023;

    float zr[E_DIM];
#pragma unroll
    for (int c = 0; c < E_DIM; ++c)
        zr[c] = z[((b * E_DIM + c) << 10) + hw];

    const float nz = np_sum64_sq(zr);   // numpy-replicated fp32 ||z||^2

    float b1 = 3.4028235e38f, b2 = 3.4028235e38f;
    int k1 = 0;

    for (int ch = 0; ch < N_E / CHUNK; ++ch) {
        __syncthreads();
        const float4* src = reinterpret_cast<const float4*>(emb + ch * CHUNK * E_DIM);
#pragma unroll
        for (int t = 0; t < (CHUNK * E_DIM / 4) / 256; ++t) {
            int i = tid + t * 256;
            int r = i >> 4;
            int c4 = i & 15;
            float4 v = src[i];
            *reinterpret_cast<float4*>(&se[r * LDSPAD + c4 * 4]) = v;
        }
        if (tid < CHUNK) sn[tid] = norms[ch * CHUNK + tid];
        __syncthreads();

        for (int j = 0; j < CHUNK / 4; ++j) {
            const int lr = (j << 2) + s;
            const float* er = &se[lr * LDSPAD];
            float a0 = 0.f, a1 = 0.f, a2 = 0.f, a3 = 0.f;
#pragma unroll
            for (int w = 0; w < E_DIM / 4; ++w) {
                float4 ev = *reinterpret_cast<const float4*>(&er[w * 4]);
                a0 += ev.x * zr[w * 4 + 0];
                a1 += ev.y * zr[w * 4 + 1];
                a2 += ev.z * zr[w * 4 + 2];
                a3 += ev.w * zr[w * 4 + 3];
            }
            float dot = (a0 + a1) + (a2 + a3);
            float d;
            {
#pragma clang fp contract(off)
                float t1 = nz + sn[lr];
                d = t1 - 2.0f * dot;
            }
            int k = ch * CHUNK + lr;
            if (d < b1) { b2 = b1; b1 = d; k1 = k; }
            else if (d < b2) { b2 = d; }
        }
    }

    // merge (best, idx, second) across the 4 split lanes
#pragma unroll
    for (int off = 1; off < 4; off <<= 1) {
        float ob1 = __shfl_xor(b1, off, 64);
        float ob2 = __shfl_xor(b2, off, 64);
        int   ok1 = __shfl_xor(k1, off, 64);
        float nb2 = fminf(fmaxf(b1, ob1), fminf(b2, ob2));
        if (ob1 < b1 || (ob1 == b1 && ok1 < k1)) { b1 = ob1; k1 = ok1; }
        b2 = nb2;
    }

    if (s == 0) {
        idx[p] = k1;
        out_idx[p] = (float)k1;
        atomicAdd(&counts[k1], 1u);
        if (b2 - b1 < 4e-5f) {   // within ~2 ulps of the fp32 d-grid: re-resolve
            unsigned int slot = atomicAdd(fixcnt, 1u);
            if (slot < FIXCAP) fixlist[slot] = p;
        }
    }
}

// Phase B: replicated-fp32-quantized exact re-resolution of flagged points.
// dot computed in fp64, rounded to fp32 (correctly-rounded == what any
// reasonable fp32 BLAS/einsum produces to within ~1e-8), then
// d = fl32( fl32(nz + ne_k) - 2*fl32(dot) ); argmin with first-index ties.
__global__ void kfix_kernel(const float* __restrict__ z, const float* __restrict__ emb,
                            const float* __restrict__ norms,
                            int* __restrict__ idx, unsigned int* __restrict__ counts,
                            float* __restrict__ out_idx,
                            const unsigned int* __restrict__ fixcnt,
                            const int* __restrict__ fixlist)
{
    __shared__ float sd[256];
    __shared__ int   si[256];
    unsigned int n = *fixcnt;
    if (n > FIXCAP) n = FIXCAP;
    for (unsigned int it = blockIdx.x; it < n; it += gridDim.x) {
        __syncthreads();
        int p = fixlist[it];
        int b = p >> 10, hw = p & 1023;
        float zr[E_DIM];
#pragma unroll
        for (int c = 0; c < E_DIM; ++c)
            zr[c] = z[((b * E_DIM + c) << 10) + hw];
        const float nz = np_sum64_sq(zr);

        float best = 3.4028235e38f; int bestk = N_E;
#pragma unroll
        for (int j = 0; j < N_E / 256; ++j) {
            int k = threadIdx.x + j * 256;
            double acc = 0.0;
            for (int c = 0; c < E_DIM; ++c)
                acc += (double)emb[k * E_DIM + c] * (double)zr[c];
            float dotf = (float)acc;
            float d;
            {
#pragma clang fp contract(off)
                float t1 = nz + norms[k];
                d = t1 - 2.0f * dotf;
            }
            if (d < best) { best = d; bestk = k; }   // ascending k: first-min kept
        }
        sd[threadIdx.x] = best; si[threadIdx.x] = bestk;
        __syncthreads();
        for (int off = 128; off > 0; off >>= 1) {
            if (threadIdx.x < off) {
                float ob = sd[threadIdx.x + off]; int ok = si[threadIdx.x + off];
                if (ob < sd[threadIdx.x] ||
                    (ob == sd[threadIdx.x] && ok < si[threadIdx.x])) {
                    sd[threadIdx.x] = ob; si[threadIdx.x] = ok;
                }
            }
            __syncthreads();
        }
        if (threadIdx.x == 0) {
            int newk = si[0], oldk = idx[p];
            if (newk != oldk) {
                idx[p] = newk;
                out_idx[p] = (float)newk;
                atomicSub(&counts[oldk], 1u);
                atomicAdd(&counts[newk], 1u);
            }
        }
    }
}

// gather z_q (B,C,H,W) + fused loss partial: loss = 1.25 * mean((z_q - z)^2)
__global__ void kzq_kernel(const float* __restrict__ z, const float* __restrict__ emb,
                           const int* __restrict__ idx,
                           float* __restrict__ zq_out, float* __restrict__ loss_accum)
{
    int gid = blockIdx.x * blockDim.x + threadIdx.x; // float4 index, 524288 total
    int f = gid << 2;
    int hw = f & 1023;
    int bc = f >> 10;
    int c = bc & 63;
    int b = bc >> 6;
    int p = (b << 10) + hw;
    int4 i4 = *reinterpret_cast<const int4*>(&idx[p]);
    float4 zv = *reinterpret_cast<const float4*>(&z[f]);
    float4 q;
    q.x = emb[(size_t)i4.x * E_DIM + c];
    q.y = emb[(size_t)i4.y * E_DIM + c];
    q.z = emb[(size_t)i4.z * E_DIM + c];
    q.w = emb[(size_t)i4.w * E_DIM + c];
    *reinterpret_cast<float4*>(&zq_out[f]) = q;
    float dx = q.x - zv.x, dy = q.y - zv.y, dz = q.z - zv.z, dw = q.w - zv.w;
    float ssum = dx * dx + dy * dy + dz * dz + dw * dw;
#pragma unroll
    for (int off = 32; off > 0; off >>= 1) ssum += __shfl_down(ssum, off, 64);
    __shared__ float wsum[4];
    int lane = threadIdx.x & 63, wid = threadIdx.x >> 6;
    if (lane == 0) wsum[wid] = ssum;
    __syncthreads();
    if (threadIdx.x == 0)
        atomicAdd(loss_accum, wsum[0] + wsum[1] + wsum[2] + wsum[3]);
}

// one-hot fill: 4096 blocks x 256 thr, 8 rows/block, float4 coalesced
__global__ void konehot_kernel(const int* __restrict__ idx, float* __restrict__ oh)
{
    int row0 = blockIdx.x * 8;
    int col = threadIdx.x << 2;
#pragma unroll
    for (int r = 0; r < 8; ++r) {
        int row = row0 + r;
        int k = idx[row];
        float4 v;
        v.x = (col + 0 == k) ? 1.f : 0.f;
        v.y = (col + 1 == k) ? 1.f : 0.f;
        v.z = (col + 2 == k) ? 1.f : 0.f;
        v.w = (col + 3 == k) ? 1.f : 0.f;
        *reinterpret_cast<float4*>(&oh[(size_t)row * N_E + col]) = v;
    }
}

__global__ void kfin_kernel(const unsigned int* __restrict__ counts,
                            const float* __restrict__ loss_accum,
                            float* __restrict__ out_loss, float* __restrict__ out_perp)
{
    int k = threadIdx.x; // 1024 threads
    float em = (float)counts[k] / (float)N_PTS;
    float v = em * logf(em + 1e-10f);
#pragma unroll
    for (int off = 32; off > 0; off >>= 1) v += __shfl_down(v, off, 64);
    __shared__ float sb[16];
    int lane = k & 63, wid = k >> 6;
    if (lane == 0) sb[wid] = v;
    __syncthreads();
    if (k == 0) {
        float ssum = 0.f;
#pragma unroll
        for (int i = 0; i < 16; ++i) ssum += sb[i];
        *out_perp = expf(-ssum);
        *out_loss = 1.25f * (*loss_accum) / 2097152.f;
    }
}

extern "C" void kernel_launch(void* const* d_in, const int* in_sizes, int n_in,
                              void* d_out, int out_size, void* d_ws, size_t ws_size,
                              hipStream_t stream) {
    const float* z   = (const float*)d_in[0];
    const float* emb = (const float*)d_in[1];
    float* out = (float*)d_out;

    float* out_loss = out;
    float* out_zq   = out + OFF_ZQ;
    float* out_perp = out + OFF_PERP;
    float* out_oh   = out + OFF_OH;
    float* out_idx  = out + OFF_IDX;

    char* ws = (char*)d_ws;
    float*        loss_accum = (float*)(ws + WS_LOSS);
    unsigned int* fixcnt     = (unsigned int*)(ws + WS_FIXCNT);
    unsigned int* counts     = (unsigned int*)(ws + WS_COUNTS);
    float*        norms      = (float*)(ws + WS_NORMS);
    int*          idx        = (int*)(ws + WS_IDX);
    int*          fixlist    = (int*)(ws + WS_FIXLIST);

    hipMemsetAsync(d_ws, 0, 8192, stream);  // loss, fixcnt, counts

    knorm_kernel<<<(N_E + 255) / 256, 256, 0, stream>>>(emb, norms);
    kargmin_kernel<<<N_PTS / 64, 256, 0, stream>>>(z, emb, norms, idx, counts,
                                                   out_idx, fixcnt, fixlist);
    kfix_kernel<<<128, 256, 0, stream>>>(z, emb, norms, idx, counts, out_idx,
                                         fixcnt, fixlist);
    kzq_kernel<<<2097152 / 4 / 256, 256, 0, stream>>>(z, emb, idx, out_zq, loss_accum);
    konehot_kernel<<<N_PTS / 8, 256, 0, stream>>>(idx, out_oh);
    kfin_kernel<<<1, 1024, 0, stream>>>(counts, loss_accum, out_loss, out_perp);
}

// Round 3
// 191.869 us; speedup vs baseline: 2.4166x; 2.4166x over previous
//
#include <hip/hip_runtime.h>

#define E_DIM 64
#define N_E   1024
#define N_PTS 32768

// d_out layout (floats):
//   [0]                      loss
//   [1 .. 1+2097152)         z_q_out (B,C,H,W)
//   [2097153]                perplexity
//   [2097154 .. +33554432)   min_encodings (N, n_e)
//   [35651586 .. +32768)     indices (as float)
#define OFF_ZQ   1
#define OFF_PERP 2097153
#define OFF_OH   2097154
#define OFF_IDX  35651586

// d_ws layout (bytes):
#define WS_LOSS    0        // float
#define WS_FIXCNT  4        // uint
#define WS_COUNTS  256      // uint[1024]
#define WS_NORMS   8192     // float[1024]
#define WS_IDX     16384    // int[32768]      (ends 147456)
#define WS_FIXLIST 147456   // int[8192]       (ends 180224)
#define FIXCAP     8192

#define CHUNK  128
#define LDSPAD 68

// numpy pairwise_sum replication for n=64 over squares:
// r[j] = sum_m fl32(a[8m+j]^2) accumulated sequentially (m ascending),
// result = ((r0+r1)+(r2+r3))+((r4+r5)+(r6+r7)).  fp32, NO contraction.
__device__ __forceinline__ float np_sum64_sq(const float* a) {
#pragma clang fp contract(off)
    float r0 = a[0] * a[0];
    float r1 = a[1] * a[1];
    float r2 = a[2] * a[2];
    float r3 = a[3] * a[3];
    float r4 = a[4] * a[4];
    float r5 = a[5] * a[5];
    float r6 = a[6] * a[6];
    float r7 = a[7] * a[7];
#pragma unroll
    for (int m = 1; m < 8; ++m) {
        r0 += a[8 * m + 0] * a[8 * m + 0];
        r1 += a[8 * m + 1] * a[8 * m + 1];
        r2 += a[8 * m + 2] * a[8 * m + 2];
        r3 += a[8 * m + 3] * a[8 * m + 3];
        r4 += a[8 * m + 4] * a[8 * m + 4];
        r5 += a[8 * m + 5] * a[8 * m + 5];
        r6 += a[8 * m + 6] * a[8 * m + 6];
        r7 += a[8 * m + 7] * a[8 * m + 7];
    }
    return ((r0 + r1) + (r2 + r3)) + ((r4 + r5) + (r6 + r7));
}

__global__ void knorm_kernel(const float* __restrict__ emb, float* __restrict__ norms) {
    int k = blockIdx.x * blockDim.x + threadIdx.x;
    if (k >= N_E) return;
    float er[E_DIM];
    const float4* e4 = reinterpret_cast<const float4*>(emb) + (size_t)k * (E_DIM / 4);
#pragma unroll
    for (int i = 0; i < E_DIM / 4; ++i)
        *reinterpret_cast<float4*>(&er[i * 4]) = e4[i];
    norms[k] = np_sum64_sq(er);
}

// Phase A: 512 blocks x 256 threads. 64 points/block, 4 threads/point.
// Computes d = fl32( fl32(nz + ne_k) - 2*dot32 ) with fast fp32 dot;
// tracks top-2; near-ties go to Phase B.
__global__ __launch_bounds__(256) void kargmin_kernel(
    const float* __restrict__ z, const float* __restrict__ emb,
    const float* __restrict__ norms,
    int* __restrict__ idx, unsigned int* __restrict__ counts,
    float* __restrict__ out_idx,
    unsigned int* __restrict__ fixcnt, int* __restrict__ fixlist)
{
    __shared__ float se[CHUNK * LDSPAD];
    __shared__ float sn[CHUNK];
    const int tid = threadIdx.x;
    const int s = tid & 3;        // code-split lane
    const int lp = tid >> 2;      // local point 0..63
    const int p = blockIdx.x * 64 + lp;
    const int b = p >> 10;
    const int hw = p & 1023;

    float zr[E_DIM];
#pragma unroll
    for (int c = 0; c < E_DIM; ++c)
        zr[c] = z[((b * E_DIM + c) << 10) + hw];

    const float nz = np_sum64_sq(zr);   // numpy-replicated fp32 ||z||^2

    float b1 = 3.4028235e38f, b2 = 3.4028235e38f;
    int k1 = 0;

    for (int ch = 0; ch < N_E / CHUNK; ++ch) {
        __syncthreads();
        const float4* src = reinterpret_cast<const float4*>(emb + ch * CHUNK * E_DIM);
#pragma unroll
        for (int t = 0; t < (CHUNK * E_DIM / 4) / 256; ++t) {
            int i = tid + t * 256;
            int r = i >> 4;
            int c4 = i & 15;
            float4 v = src[i];
            *reinterpret_cast<float4*>(&se[r * LDSPAD + c4 * 4]) = v;
        }
        if (tid < CHUNK) sn[tid] = norms[ch * CHUNK + tid];
        __syncthreads();

        for (int j = 0; j < CHUNK / 4; ++j) {
            const int lr = (j << 2) + s;
            const float* er = &se[lr * LDSPAD];
            float a0 = 0.f, a1 = 0.f, a2 = 0.f, a3 = 0.f;
#pragma unroll
            for (int w = 0; w < E_DIM / 4; ++w) {
                float4 ev = *reinterpret_cast<const float4*>(&er[w * 4]);
                a0 += ev.x * zr[w * 4 + 0];
                a1 += ev.y * zr[w * 4 + 1];
                a2 += ev.z * zr[w * 4 + 2];
                a3 += ev.w * zr[w * 4 + 3];
            }
            float dot = (a0 + a1) + (a2 + a3);
            float d;
            {
#pragma clang fp contract(off)
                float t1 = nz + sn[lr];
                d = t1 - 2.0f * dot;
            }
            int k = ch * CHUNK + lr;
            if (d < b1) { b2 = b1; b1 = d; k1 = k; }
            else if (d < b2) { b2 = d; }
        }
    }

    // merge (best, idx, second) across the 4 split lanes
#pragma unroll
    for (int off = 1; off < 4; off <<= 1) {
        float ob1 = __shfl_xor(b1, off, 64);
        float ob2 = __shfl_xor(b2, off, 64);
        int   ok1 = __shfl_xor(k1, off, 64);
        float nb2 = fminf(fmaxf(b1, ob1), fminf(b2, ob2));
        if (ob1 < b1 || (ob1 == b1 && ok1 < k1)) { b1 = ob1; k1 = ok1; }
        b2 = nb2;
    }

    if (s == 0) {
        idx[p] = k1;
        out_idx[p] = (float)k1;
        atomicAdd(&counts[k1], 1u);
        // flag if within ~2 ulps of the fp32 d-grid (grid step 7.6e-6 for
        // d<64, 1.5e-5 for d<128, 3.1e-5 for d<256)
        float gap = b2 - b1;
        if (gap < 4e-5f || (b1 >= 128.f && gap < 6.5e-5f)) {
            unsigned int slot = atomicAdd(fixcnt, 1u);
            if (slot < FIXCAP) fixlist[slot] = p;
        }
    }
}

// Phase B: replicated-fp32-quantized exact re-resolution of flagged points.
// dot computed in fp64 (correctly rounded to fp32), then
// d = fl32( fl32(nz + ne_k) - 2*fl32(dot) ); argmin with first-index ties.
// Fully unrolled: zr stays in VGPRs (no scratch), 4 fp64 acc chains for ILP.
__global__ __launch_bounds__(256) void kfix_kernel(
    const float* __restrict__ z, const float* __restrict__ emb,
    const float* __restrict__ norms,
    int* __restrict__ idx, unsigned int* __restrict__ counts,
    float* __restrict__ out_idx,
    const unsigned int* __restrict__ fixcnt,
    const int* __restrict__ fixlist)
{
    __shared__ float sd[256];
    __shared__ int   si[256];
    unsigned int n = *fixcnt;
    if (n > FIXCAP) n = FIXCAP;
    for (unsigned int it = blockIdx.x; it < n; it += gridDim.x) {
        __syncthreads();   // protect sd/si reuse across stride iterations
        const int p = fixlist[it];
        const int b = p >> 10, hw = p & 1023;
        float zr[E_DIM];
#pragma unroll
        for (int c = 0; c < E_DIM; ++c)
            zr[c] = z[((b * E_DIM + c) << 10) + hw];
        const float nz = np_sum64_sq(zr);

        const int t = threadIdx.x;
        const float* e0 = emb + (size_t)t * E_DIM;
        const float* e1 = e0 + 256 * E_DIM;
        const float* e2 = e1 + 256 * E_DIM;
        const float* e3 = e2 + 256 * E_DIM;
        double a0 = 0.0, a1 = 0.0, a2 = 0.0, a3 = 0.0;
#pragma unroll
        for (int c = 0; c < E_DIM; ++c) {
            const double zv = (double)zr[c];
            a0 += (double)e0[c] * zv;
            a1 += (double)e1[c] * zv;
            a2 += (double)e2[c] * zv;
            a3 += (double)e3[c] * zv;
        }
        float d0, d1, d2, d3;
        {
#pragma clang fp contract(off)
            float t0 = nz + norms[t];
            float t1 = nz + norms[t + 256];
            float t2 = nz + norms[t + 512];
            float t3 = nz + norms[t + 768];
            d0 = t0 - 2.0f * (float)a0;
            d1 = t1 - 2.0f * (float)a1;
            d2 = t2 - 2.0f * (float)a2;
            d3 = t3 - 2.0f * (float)a3;
        }
        float best = d0; int bestk = t;                    // ascending k:
        if (d1 < best) { best = d1; bestk = t + 256; }     // strict < keeps
        if (d2 < best) { best = d2; bestk = t + 512; }     // first index
        if (d3 < best) { best = d3; bestk = t + 768; }

        sd[t] = best; si[t] = bestk;
        __syncthreads();
        for (int off = 128; off > 0; off >>= 1) {
            if (t < off) {
                float ob = sd[t + off]; int ok = si[t + off];
                if (ob < sd[t] || (ob == sd[t] && ok < si[t])) {
                    sd[t] = ob; si[t] = ok;
                }
            }
            __syncthreads();
        }
        if (t == 0) {
            int newk = si[0], oldk = idx[p];
            if (newk != oldk) {
                idx[p] = newk;
                out_idx[p] = (float)newk;
                atomicSub(&counts[oldk], 1u);
                atomicAdd(&counts[newk], 1u);
            }
        }
    }
}

// gather z_q (B,C,H,W) + fused loss partial: loss = 1.25 * mean((z_q - z)^2)
__global__ void kzq_kernel(const float* __restrict__ z, const float* __restrict__ emb,
                           const int* __restrict__ idx,
                           float* __restrict__ zq_out, float* __restrict__ loss_accum)
{
    int gid = blockIdx.x * blockDim.x + threadIdx.x; // float4 index, 524288 total
    int f = gid << 2;
    int hw = f & 1023;
    int bc = f >> 10;
    int c = bc & 63;
    int b = bc >> 6;
    int p = (b << 10) + hw;
    int4 i4 = *reinterpret_cast<const int4*>(&idx[p]);
    float4 zv = *reinterpret_cast<const float4*>(&z[f]);
    float4 q;
    q.x = emb[(size_t)i4.x * E_DIM + c];
    q.y = emb[(size_t)i4.y * E_DIM + c];
    q.z = emb[(size_t)i4.z * E_DIM + c];
    q.w = emb[(size_t)i4.w * E_DIM + c];
    *reinterpret_cast<float4*>(&zq_out[f]) = q;
    float dx = q.x - zv.x, dy = q.y - zv.y, dz = q.z - zv.z, dw = q.w - zv.w;
    float ssum = dx * dx + dy * dy + dz * dz + dw * dw;
#pragma unroll
    for (int off = 32; off > 0; off >>= 1) ssum += __shfl_down(ssum, off, 64);
    __shared__ float wsum[4];
    int lane = threadIdx.x & 63, wid = threadIdx.x >> 6;
    if (lane == 0) wsum[wid] = ssum;
    __syncthreads();
    if (threadIdx.x == 0)
        atomicAdd(loss_accum, wsum[0] + wsum[1] + wsum[2] + wsum[3]);
}

// one-hot fill: 4096 blocks x 256 thr, 8 rows/block, float4 coalesced
__global__ void konehot_kernel(const int* __restrict__ idx, float* __restrict__ oh)
{
    int row0 = blockIdx.x * 8;
    int col = threadIdx.x << 2;
#pragma unroll
    for (int r = 0; r < 8; ++r) {
        int row = row0 + r;
        int k = idx[row];
        float4 v;
        v.x = (col + 0 == k) ? 1.f : 0.f;
        v.y = (col + 1 == k) ? 1.f : 0.f;
        v.z = (col + 2 == k) ? 1.f : 0.f;
        v.w = (col + 3 == k) ? 1.f : 0.f;
        *reinterpret_cast<float4*>(&oh[(size_t)row * N_E + col]) = v;
    }
}

__global__ void kfin_kernel(const unsigned int* __restrict__ counts,
                            const float* __restrict__ loss_accum,
                            float* __restrict__ out_loss, float* __restrict__ out_perp)
{
    int k = threadIdx.x; // 1024 threads
    float em = (float)counts[k] / (float)N_PTS;
    float v = em * logf(em + 1e-10f);
#pragma unroll
    for (int off = 32; off > 0; off >>= 1) v += __shfl_down(v, off, 64);
    __shared__ float sb[16];
    int lane = k & 63, wid = k >> 6;
    if (lane == 0) sb[wid] = v;
    __syncthreads();
    if (k == 0) {
        float ssum = 0.f;
#pragma unroll
        for (int i = 0; i < 16; ++i) ssum += sb[i];
        *out_perp = expf(-ssum);
        *out_loss = 1.25f * (*loss_accum) / 2097152.f;
    }
}

extern "C" void kernel_launch(void* const* d_in, const int* in_sizes, int n_in,
                              void* d_out, int out_size, void* d_ws, size_t ws_size,
                              hipStream_t stream) {
    const float* z   = (const float*)d_in[0];
    const float* emb = (const float*)d_in[1];
    float* out = (float*)d_out;

    float* out_loss = out;
    float* out_zq   = out + OFF_ZQ;
    float* out_perp = out + OFF_PERP;
    float* out_oh   = out + OFF_OH;
    float* out_idx  = out + OFF_IDX;

    char* ws = (char*)d_ws;
    float*        loss_accum = (float*)(ws + WS_LOSS);
    unsigned int* fixcnt     = (unsigned int*)(ws + WS_FIXCNT);
    unsigned int* counts     = (unsigned int*)(ws + WS_COUNTS);
    float*        norms      = (float*)(ws + WS_NORMS);
    int*          idx        = (int*)(ws + WS_IDX);
    int*          fixlist    = (int*)(ws + WS_FIXLIST);

    hipMemsetAsync(d_ws, 0, 8192, stream);  // loss, fixcnt, counts

    knorm_kernel<<<(N_E + 255) / 256, 256, 0, stream>>>(emb, norms);
    kargmin_kernel<<<N_PTS / 64, 256, 0, stream>>>(z, emb, norms, idx, counts,
                                                   out_idx, fixcnt, fixlist);
    kfix_kernel<<<512, 256, 0, stream>>>(z, emb, norms, idx, counts, out_idx,
                                         fixcnt, fixlist);
    kzq_kernel<<<2097152 / 4 / 256, 256, 0, stream>>>(z, emb, idx, out_zq, loss_accum);
    konehot_kernel<<<N_PTS / 8, 256, 0, stream>>>(idx, out_oh);
    kfin_kernel<<<1, 1024, 0, stream>>>(counts, loss_accum, out_loss, out_perp);
}

// Round 4
// 143.864 us; speedup vs baseline: 3.2230x; 1.3337x over previous
//
#include <hip/hip_runtime.h>

#define E_DIM 64
#define N_E   1024
#define N_PTS 32768

// d_out layout (floats):
#define OFF_ZQ   1
#define OFF_PERP 2097153
#define OFF_OH   2097154
#define OFF_IDX  35651586

// d_ws layout (bytes), total needed ~573 KB:
#define WS_LOSS    0        // float
#define WS_FIXCNT  4        // uint
#define WS_COUNTS  256      // uint[1024]
#define WS_NORMS   8192     // float[1024]        (ne, from eprep)
#define WS_IDX     16384    // int[32768]         (ends 147456)
#define WS_FIXLIST 147456   // int[8192]          (ends 180224)
#define WS_NZ      180224   // float[32768]       (ends 311296)
#define WS_EBHL    311296   // ushort[1024*128]   hi[64],lo[64] per code (ends 573440)
#define FIXCAP     8192

typedef __attribute__((ext_vector_type(8))) short short8;
typedef __attribute__((ext_vector_type(4))) float f32x4;
typedef __attribute__((ext_vector_type(4))) unsigned int u32x4;

// numpy pairwise_sum replication for n=64 over squares (fp32, no contraction)
__device__ __forceinline__ float np_sum64_sq(const float* a) {
#pragma clang fp contract(off)
    float r0 = a[0] * a[0];
    float r1 = a[1] * a[1];
    float r2 = a[2] * a[2];
    float r3 = a[3] * a[3];
    float r4 = a[4] * a[4];
    float r5 = a[5] * a[5];
    float r6 = a[6] * a[6];
    float r7 = a[7] * a[7];
#pragma unroll
    for (int m = 1; m < 8; ++m) {
        r0 += a[8 * m + 0] * a[8 * m + 0];
        r1 += a[8 * m + 1] * a[8 * m + 1];
        r2 += a[8 * m + 2] * a[8 * m + 2];
        r3 += a[8 * m + 3] * a[8 * m + 3];
        r4 += a[8 * m + 4] * a[8 * m + 4];
        r5 += a[8 * m + 5] * a[8 * m + 5];
        r6 += a[8 * m + 6] * a[8 * m + 6];
        r7 += a[8 * m + 7] * a[8 * m + 7];
    }
    return ((r0 + r1) + (r2 + r3)) + ((r4 + r5) + (r6 + r7));
}

// round-to-nearest-even fp32 -> bf16 (bit pattern)
__device__ __forceinline__ unsigned short rn_bf16(float f) {
    unsigned int u = __float_as_uint(f);
    return (unsigned short)((u + 0x7FFFu + ((u >> 16) & 1u)) >> 16);
}
__device__ __forceinline__ float bf16_to_f(unsigned short h) {
    return __uint_as_float(((unsigned int)h) << 16);
}

// prep: codebook -> hi/lo bf16 (linear layout) + ||e||^2 (np-replicated)
__global__ void eprep_kernel(const float* __restrict__ emb,
                             unsigned short* __restrict__ ebhl,
                             float* __restrict__ norms) {
    int k = blockIdx.x * blockDim.x + threadIdx.x;
    if (k >= N_E) return;
    float er[E_DIM];
    const float4* e4 = reinterpret_cast<const float4*>(emb) + (size_t)k * (E_DIM / 4);
#pragma unroll
    for (int i = 0; i < E_DIM / 4; ++i)
        *reinterpret_cast<float4*>(&er[i * 4]) = e4[i];
    norms[k] = np_sum64_sq(er);
    unsigned int* rh = (unsigned int*)(ebhl + (size_t)k * 128);
    unsigned int* rl = rh + 32;
#pragma unroll
    for (int c = 0; c < E_DIM; c += 2) {
        unsigned short h0 = rn_bf16(er[c]);
        unsigned short h1 = rn_bf16(er[c + 1]);
        unsigned short l0 = rn_bf16(er[c] - bf16_to_f(h0));
        unsigned short l1 = rn_bf16(er[c + 1] - bf16_to_f(h1));
        rh[c / 2] = (unsigned int)h0 | ((unsigned int)h1 << 16);
        rl[c / 2] = (unsigned int)l0 | ((unsigned int)l1 << 16);
    }
}

// prep: per-point ||z||^2 (np-replicated); coalesced strided reads
__global__ void kznorm_kernel(const float* __restrict__ z, float* __restrict__ nz) {
    int p = blockIdx.x * blockDim.x + threadIdx.x;
    int b = p >> 10, hw = p & 1023;
    float zr[E_DIM];
#pragma unroll
    for (int c = 0; c < E_DIM; ++c)
        zr[c] = z[((b * E_DIM + c) << 10) + hw];
    nz[p] = np_sum64_sq(zr);
}

// Phase A: MFMA split-bf16 distance + argmin.
// 512 blocks x 256 thr (4 waves). Block = 64 points; wave = 16 points x 1024 codes.
__global__ __launch_bounds__(256) void kargmin_kernel(
    const float* __restrict__ z, const unsigned short* __restrict__ ebhl,
    const float* __restrict__ norms, const float* __restrict__ nzG,
    int* __restrict__ idx, unsigned int* __restrict__ counts,
    float* __restrict__ out_idx,
    unsigned int* __restrict__ fixcnt, int* __restrict__ fixlist)
{
    __shared__ float szt[64][68];             // z tile (17408 B)
    __shared__ unsigned short sbuf[2][8192];  // 2 x 16 KB code-group dbuf
    __shared__ float sne[N_E];                // 4 KB

    const int tid = threadIdx.x;
    const int wave = tid >> 6;
    const int lane = tid & 63;
    const int lc = lane & 15;      // MFMA col / A-row lane id
    const int rg = lane >> 4;      // row group 0..3
    const int blk = blockIdx.x;
    const int pbase = blk * 64;
    const int b = pbase >> 10;
    const int hw0 = pbase & 1023;

    // stage ne (1024 floats) and z tile (64 pts x 64 dims, coalesced per-c)
    *reinterpret_cast<float4*>(&sne[tid * 4]) =
        *reinterpret_cast<const float4*>(norms + tid * 4);
    {
        const int c0 = tid >> 6, pt = tid & 63;
#pragma unroll
        for (int cg = 0; cg < 16; ++cg) {
            int c = cg * 4 + c0;
            szt[pt][c] = z[((b * E_DIM + c) << 10) + hw0 + pt];
        }
    }
    __syncthreads();

    // A-fragments: lane holds A row (pt) = lc, dims rg*8+j (K0) / 32+rg*8+j (K1)
    const int pa = wave * 16 + lc;
    float4 zv0 = *reinterpret_cast<const float4*>(&szt[pa][rg * 8]);
    float4 zv1 = *reinterpret_cast<const float4*>(&szt[pa][rg * 8 + 4]);
    float4 zv2 = *reinterpret_cast<const float4*>(&szt[pa][32 + rg * 8]);
    float4 zv3 = *reinterpret_cast<const float4*>(&szt[pa][32 + rg * 8 + 4]);
    float zt0[8] = {zv0.x, zv0.y, zv0.z, zv0.w, zv1.x, zv1.y, zv1.z, zv1.w};
    float zt1[8] = {zv2.x, zv2.y, zv2.z, zv2.w, zv3.x, zv3.y, zv3.z, zv3.w};
    short8 zh0, zl0, zh1, zl1;
#pragma unroll
    for (int j = 0; j < 8; ++j) {
        unsigned short h0 = rn_bf16(zt0[j]);
        zh0[j] = (short)h0;
        zl0[j] = (short)rn_bf16(zt0[j] - bf16_to_f(h0));
        unsigned short h1 = rn_bf16(zt1[j]);
        zh1[j] = (short)h1;
        zl1[j] = (short)rn_bf16(zt1[j] - bf16_to_f(h1));
    }

    // nz for this lane's 4 output rows (C/D: row = rg*4 + r)
    float nzr[4];
#pragma unroll
    for (int r = 0; r < 4; ++r)
        nzr[r] = nzG[pbase + wave * 16 + rg * 4 + r];

    // codebook group staging: group = 64 codes = 16 KB; load->regs then swizzled ds_write
    u32x4 ldreg[4];
#define GLD(og) {                                                             \
        const u32x4* gp = reinterpret_cast<const u32x4*>(ebhl) + (og) * 1024; \
        _Pragma("unroll")                                                     \
        for (int i = 0; i < 4; ++i) ldreg[i] = gp[tid + i * 256];             \
    }
#define SWR(dstbuf) {                                                         \
        _Pragma("unroll")                                                     \
        for (int i = 0; i < 4; ++i) {                                         \
            int gci = tid + i * 256;                                          \
            int code = gci >> 4, cb = gci & 15;                               \
            int cbs = cb ^ (code & 7);                                        \
            *reinterpret_cast<u32x4*>(                                        \
                &(dstbuf)[(code >> 4) * 2048 + (code & 15) * 128 + cbs * 8])  \
                = ldreg[i];                                                   \
        }                                                                     \
    }

    GLD(0);
    SWR(sbuf[0]);
    __syncthreads();

    float b1[4] = {3.4028235e38f, 3.4028235e38f, 3.4028235e38f, 3.4028235e38f};
    float b2[4] = {3.4028235e38f, 3.4028235e38f, 3.4028235e38f, 3.4028235e38f};
    int k1[4] = {0, 0, 0, 0};
    const int swz = (lc & 7);

    for (int og = 0; og < 16; ++og) {
        const int cur = og & 1;
        if (og < 15) GLD(og + 1);
#pragma unroll
        for (int t = 0; t < 4; ++t) {
            const unsigned short* sb = &sbuf[cur][t * 2048 + lc * 128];
            short8 eh0 = *reinterpret_cast<const short8*>(sb + ((rg     ) ^ swz) * 8);
            short8 eh1 = *reinterpret_cast<const short8*>(sb + ((rg + 4 ) ^ swz) * 8);
            short8 el0 = *reinterpret_cast<const short8*>(sb + ((rg + 8 ) ^ swz) * 8);
            short8 el1 = *reinterpret_cast<const short8*>(sb + ((rg + 12) ^ swz) * 8);
            f32x4 pA = {0.f, 0.f, 0.f, 0.f};
            f32x4 pB = {0.f, 0.f, 0.f, 0.f};
            pA = __builtin_amdgcn_mfma_f32_16x16x32_bf16(zh0, eh0, pA, 0, 0, 0);
            pA = __builtin_amdgcn_mfma_f32_16x16x32_bf16(zh1, eh1, pA, 0, 0, 0);
            pB = __builtin_amdgcn_mfma_f32_16x16x32_bf16(zh0, el0, pB, 0, 0, 0);
            pB = __builtin_amdgcn_mfma_f32_16x16x32_bf16(zh1, el1, pB, 0, 0, 0);
            pB = __builtin_amdgcn_mfma_f32_16x16x32_bf16(zl0, eh0, pB, 0, 0, 0);
            pB = __builtin_amdgcn_mfma_f32_16x16x32_bf16(zl1, eh1, pB, 0, 0, 0);
            const int code = (og * 4 + t) * 16 + lc;
            const float ne_c = sne[code];
#pragma unroll
            for (int r = 0; r < 4; ++r) {
                float t1 = nzr[r] + ne_c;
                float d = fmaf(-2.0f, pA[r] + pB[r], t1);
                if (d < b1[r]) { b2[r] = b1[r]; b1[r] = d; k1[r] = code; }
                else if (d < b2[r]) { b2[r] = d; }
            }
        }
        if (og < 15) SWR(sbuf[cur ^ 1]);
        __syncthreads();
    }

    // merge top-2 across the 16 code-column lanes (same rg group)
#pragma unroll
    for (int off = 1; off < 16; off <<= 1) {
#pragma unroll
        for (int r = 0; r < 4; ++r) {
            float ob1 = __shfl_xor(b1[r], off, 64);
            float ob2 = __shfl_xor(b2[r], off, 64);
            int   ok1 = __shfl_xor(k1[r], off, 64);
            float nb2 = fminf(fmaxf(b1[r], ob1), fminf(b2[r], ob2));
            if (ob1 < b1[r] || (ob1 == b1[r] && ok1 < k1[r])) { b1[r] = ob1; k1[r] = ok1; }
            b2[r] = nb2;
        }
    }

    if (lc == 0) {
#pragma unroll
        for (int r = 0; r < 4; ++r) {
            int p = pbase + wave * 16 + rg * 4 + r;
            idx[p] = k1[r];
            out_idx[p] = (float)k1[r];
            atomicAdd(&counts[k1[r]], 1u);
            float gap = b2[r] - b1[r];
            if (gap < 4e-5f || (b1[r] >= 128.f && gap < 6.5e-5f)) {
                unsigned int slot = atomicAdd(fixcnt, 1u);
                if (slot < FIXCAP) fixlist[slot] = p;
            }
        }
    }
}

// Phase B: replicated-fp32-quantized exact re-resolution of flagged points.
__global__ __launch_bounds__(256) void kfix_kernel(
    const float* __restrict__ z, const float* __restrict__ emb,
    const float* __restrict__ norms,
    int* __restrict__ idx, unsigned int* __restrict__ counts,
    float* __restrict__ out_idx,
    const unsigned int* __restrict__ fixcnt,
    const int* __restrict__ fixlist)
{
    __shared__ float sd[256];
    __shared__ int   si[256];
    unsigned int n = *fixcnt;
    if (n > FIXCAP) n = FIXCAP;
    for (unsigned int it = blockIdx.x; it < n; it += gridDim.x) {
        __syncthreads();
        const int p = fixlist[it];
        const int b = p >> 10, hw = p & 1023;
        float zr[E_DIM];
#pragma unroll
        for (int c = 0; c < E_DIM; ++c)
            zr[c] = z[((b * E_DIM + c) << 10) + hw];
        const float nz = np_sum64_sq(zr);

        const int t = threadIdx.x;
        const float* e0 = emb + (size_t)t * E_DIM;
        const float* e1 = e0 + 256 * E_DIM;
        const float* e2 = e1 + 256 * E_DIM;
        const float* e3 = e2 + 256 * E_DIM;
        double a0 = 0.0, a1 = 0.0, a2 = 0.0, a3 = 0.0;
#pragma unroll
        for (int c = 0; c < E_DIM; ++c) {
            const double zv = (double)zr[c];
            a0 += (double)e0[c] * zv;
            a1 += (double)e1[c] * zv;
            a2 += (double)e2[c] * zv;
            a3 += (double)e3[c] * zv;
        }
        float d0, d1, d2, d3;
        {
#pragma clang fp contract(off)
            float t0 = nz + norms[t];
            float t1 = nz + norms[t + 256];
            float t2 = nz + norms[t + 512];
            float t3 = nz + norms[t + 768];
            d0 = t0 - 2.0f * (float)a0;
            d1 = t1 - 2.0f * (float)a1;
            d2 = t2 - 2.0f * (float)a2;
            d3 = t3 - 2.0f * (float)a3;
        }
        float best = d0; int bestk = t;
        if (d1 < best) { best = d1; bestk = t + 256; }
        if (d2 < best) { best = d2; bestk = t + 512; }
        if (d3 < best) { best = d3; bestk = t + 768; }

        sd[t] = best; si[t] = bestk;
        __syncthreads();
        for (int off = 128; off > 0; off >>= 1) {
            if (t < off) {
                float ob = sd[t + off]; int ok = si[t + off];
                if (ob < sd[t] || (ob == sd[t] && ok < si[t])) {
                    sd[t] = ob; si[t] = ok;
                }
            }
            __syncthreads();
        }
        if (t == 0) {
            int newk = si[0], oldk = idx[p];
            if (newk != oldk) {
                idx[p] = newk;
                out_idx[p] = (float)newk;
                atomicSub(&counts[oldk], 1u);
                atomicAdd(&counts[newk], 1u);
            }
        }
    }
}

// gather z_q (B,C,H,W) + fused loss partial: loss = 1.25 * mean((z_q - z)^2)
__global__ void kzq_kernel(const float* __restrict__ z, const float* __restrict__ emb,
                           const int* __restrict__ idx,
                           float* __restrict__ zq_out, float* __restrict__ loss_accum)
{
    int gid = blockIdx.x * blockDim.x + threadIdx.x;
    int f = gid << 2;
    int hw = f & 1023;
    int bc = f >> 10;
    int c = bc & 63;
    int b = bc >> 6;
    int p = (b << 10) + hw;
    int4 i4 = *reinterpret_cast<const int4*>(&idx[p]);
    float4 zv = *reinterpret_cast<const float4*>(&z[f]);
    float4 q;
    q.x = emb[(size_t)i4.x * E_DIM + c];
    q.y = emb[(size_t)i4.y * E_DIM + c];
    q.z = emb[(size_t)i4.z * E_DIM + c];
    q.w = emb[(size_t)i4.w * E_DIM + c];
    *reinterpret_cast<float4*>(&zq_out[f]) = q;
    float dx = q.x - zv.x, dy = q.y - zv.y, dz = q.z - zv.z, dw = q.w - zv.w;
    float ssum = dx * dx + dy * dy + dz * dz + dw * dw;
#pragma unroll
    for (int off = 32; off > 0; off >>= 1) ssum += __shfl_down(ssum, off, 64);
    __shared__ float wsum[4];
    int lane = threadIdx.x & 63, wid = threadIdx.x >> 6;
    if (lane == 0) wsum[wid] = ssum;
    __syncthreads();
    if (threadIdx.x == 0)
        atomicAdd(loss_accum, wsum[0] + wsum[1] + wsum[2] + wsum[3]);
}

// one-hot fill: float4 coalesced
__global__ void konehot_kernel(const int* __restrict__ idx, float* __restrict__ oh)
{
    int row0 = blockIdx.x * 8;
    int col = threadIdx.x << 2;
#pragma unroll
    for (int r = 0; r < 8; ++r) {
        int row = row0 + r;
        int k = idx[row];
        float4 v;
        v.x = (col + 0 == k) ? 1.f : 0.f;
        v.y = (col + 1 == k) ? 1.f : 0.f;
        v.z = (col + 2 == k) ? 1.f : 0.f;
        v.w = (col + 3 == k) ? 1.f : 0.f;
        *reinterpret_cast<float4*>(&oh[(size_t)row * N_E + col]) = v;
    }
}

__global__ void kfin_kernel(const unsigned int* __restrict__ counts,
                            const float* __restrict__ loss_accum,
                            float* __restrict__ out_loss, float* __restrict__ out_perp)
{
    int k = threadIdx.x;
    float em = (float)counts[k] / (float)N_PTS;
    float v = em * logf(em + 1e-10f);
#pragma unroll
    for (int off = 32; off > 0; off >>= 1) v += __shfl_down(v, off, 64);
    __shared__ float sb[16];
    int lane = k & 63, wid = k >> 6;
    if (lane == 0) sb[wid] = v;
    __syncthreads();
    if (k == 0) {
        float ssum = 0.f;
#pragma unroll
        for (int i = 0; i < 16; ++i) ssum += sb[i];
        *out_perp = expf(-ssum);
        *out_loss = 1.25f * (*loss_accum) / 2097152.f;
    }
}

extern "C" void kernel_launch(void* const* d_in, const int* in_sizes, int n_in,
                              void* d_out, int out_size, void* d_ws, size_t ws_size,
                              hipStream_t stream) {
    const float* z   = (const float*)d_in[0];
    const float* emb = (const float*)d_in[1];
    float* out = (float*)d_out;

    float* out_loss = out;
    float* out_zq   = out + OFF_ZQ;
    float* out_perp = out + OFF_PERP;
    float* out_oh   = out + OFF_OH;
    float* out_idx  = out + OFF_IDX;

    char* ws = (char*)d_ws;
    float*          loss_accum = (float*)(ws + WS_LOSS);
    unsigned int*   fixcnt     = (unsigned int*)(ws + WS_FIXCNT);
    unsigned int*   counts     = (unsigned int*)(ws + WS_COUNTS);
    float*          norms      = (float*)(ws + WS_NORMS);
    int*            idx        = (int*)(ws + WS_IDX);
    int*            fixlist    = (int*)(ws + WS_FIXLIST);
    float*          nz         = (float*)(ws + WS_NZ);
    unsigned short* ebhl       = (unsigned short*)(ws + WS_EBHL);

    hipMemsetAsync(d_ws, 0, 8192, stream);  // loss, fixcnt, counts

    eprep_kernel<<<(N_E + 255) / 256, 256, 0, stream>>>(emb, ebhl, norms);
    kznorm_kernel<<<N_PTS / 256, 256, 0, stream>>>(z, nz);
    kargmin_kernel<<<N_PTS / 64, 256, 0, stream>>>(z, ebhl, norms, nz, idx, counts,
                                                   out_idx, fixcnt, fixlist);
    kfix_kernel<<<512, 256, 0, stream>>>(z, emb, norms, idx, counts, out_idx,
                                         fixcnt, fixlist);
    kzq_kernel<<<2097152 / 4 / 256, 256, 0, stream>>>(z, emb, idx, out_zq, loss_accum);
    konehot_kernel<<<N_PTS / 8, 256, 0, stream>>>(idx, out_oh);
    kfin_kernel<<<1, 1024, 0, stream>>>(counts, loss_accum, out_loss, out_perp);
}